// Round 1
// baseline (343.375 us; speedup 1.0000x reference)
//
#include <hip/hip_runtime.h>
#include <cmath>
#include <cstdint>

namespace {

constexpr int kLevels = 8;
constexpr uint32_t kT = 1u << 16;
constexpr uint32_t kPrime1 = 2654435761u;
constexpr uint32_t kPrime2 = 805459861u;

struct LevelParams {
    float scale[kLevels];
    uint32_t res[kLevels];
    uint32_t hashed_mask;
};

__global__ __launch_bounds__(256) void ngp_mask_kernel(
    const float* __restrict__ uvi,
    const float* __restrict__ table,
    const float* __restrict__ W1,
    const float* __restrict__ b1,
    const float* __restrict__ W2,
    const float* __restrict__ b2,
    float* __restrict__ out,
    int n, LevelParams lp)
{
    const int i = blockIdx.x * blockDim.x + threadIdx.x;
    if (i >= n) return;

    const float ux = uvi[3 * i + 0];
    const float uy = uvi[3 * i + 1];
    const float uz = uvi[3 * i + 2];

    const float2* __restrict__ tb = reinterpret_cast<const float2*>(table);

    float enc[2 * kLevels];

    #pragma unroll
    for (int l = 0; l < kLevels; ++l) {
        const float s = lp.scale[l];
        // match jax: mul then add (no fma contraction) so floor boundaries agree
        const float posx = __fadd_rn(__fmul_rn(ux, s), 0.5f);
        const float posy = __fadd_rn(__fmul_rn(uy, s), 0.5f);
        const float posz = __fadd_rn(__fmul_rn(uz, s), 0.5f);
        const float fx = floorf(posx), fy = floorf(posy), fz = floorf(posz);
        const float wx = __fsub_rn(posx, fx);
        const float wy = __fsub_rn(posy, fy);
        const float wz = __fsub_rn(posz, fz);
        const uint32_t x0 = (uint32_t)fx, y0 = (uint32_t)fy, z0 = (uint32_t)fz;

        const bool hashed = (lp.hashed_mask >> l) & 1u;

        // per-axis index components: one mul per axis, +const for the +1 corner
        uint32_t hx0, hx1, hy0, hy1, hz0, hz1;
        if (hashed) {
            hx0 = x0;             hx1 = x0 + 1u;
            hy0 = y0 * kPrime1;   hy1 = hy0 + kPrime1;
            hz0 = z0 * kPrime2;   hz1 = hz0 + kPrime2;
        } else {
            const uint32_t r  = lp.res[l];
            const uint32_t r2 = r * r;
            hx0 = x0;             hx1 = x0 + 1u;
            hy0 = y0 * r;         hy1 = hy0 + r;
            hz0 = z0 * r2;        hz1 = hz0 + r2;
        }

        const float wx0 = __fsub_rn(1.f, wx);
        const float wy0 = __fsub_rn(1.f, wy);
        const float wz0 = __fsub_rn(1.f, wz);
        const float w00 = __fmul_rn(wx0, wy0);
        const float w10 = __fmul_rn(wx,  wy0);
        const float w01 = __fmul_rn(wx0, wy);
        const float w11 = __fmul_rn(wx,  wy);

        const uint32_t base = (uint32_t)l << 16;
        float a0 = 0.f, a1 = 0.f;

        #pragma unroll
        for (int c = 0; c < 8; ++c) {
            const uint32_t hx = (c & 1) ? hx1 : hx0;
            const uint32_t hy = (c & 2) ? hy1 : hy0;
            const uint32_t hz = (c & 4) ? hz1 : hz0;
            uint32_t idxc;
            if (hashed) idxc = (hx ^ hy ^ hz) & (kT - 1u);
            else        idxc = hx + hy + hz;
            const float wxy = (c & 2) ? ((c & 1) ? w11 : w01)
                                      : ((c & 1) ? w10 : w00);
            const float wcc = __fmul_rn(wxy, (c & 4) ? wz : wz0);
            const float2 t = tb[base + idxc];
            a0 = __fadd_rn(a0, __fmul_rn(t.x, wcc));
            a1 = __fadd_rn(a1, __fmul_rn(t.y, wcc));
        }
        enc[2 * l + 0] = a0;
        enc[2 * l + 1] = a1;
    }

    // MLP: h = relu(enc @ W1 + b1); logit = h @ W2 + b2; sigmoid
    // j-streamed so only enc[16] + logit stay live; W1/b1/W2 indices are
    // compile-time -> uniform scalar loads (SMEM pipe), VMEM stays free.
    float logit = b2[0];
    #pragma unroll
    for (int j = 0; j < 64; ++j) {
        float h = b1[j];
        #pragma unroll
        for (int k = 0; k < 16; ++k)
            h = fmaf(enc[k], W1[k * 64 + j], h);
        h = fmaxf(h, 0.f);
        logit = fmaf(h, W2[j], logit);
    }

    out[i] = 1.f / (1.f + __expf(-logit));
}

} // namespace

extern "C" void kernel_launch(void* const* d_in, const int* in_sizes, int n_in,
                              void* d_out, int out_size, void* d_ws, size_t ws_size,
                              hipStream_t stream)
{
    const float* uvi   = (const float*)d_in[0];
    const float* table = (const float*)d_in[1];
    const float* W1    = (const float*)d_in[2];
    const float* b1    = (const float*)d_in[3];
    const float* W2    = (const float*)d_in[4];
    const float* b2    = (const float*)d_in[5];
    float* out = (float*)d_out;

    const int n = in_sizes[0] / 3;

    // Replicate numpy's double-precision level math exactly:
    // B = exp(log(2048/16)/7); scale_l = 16*B^l - 1; res = ceil(scale)+1
    LevelParams lp;
    const double B = exp(log(2048.0 / 16.0) / (double)(kLevels - 1));
    uint32_t mask = 0;
    for (int l = 0; l < kLevels; ++l) {
        const double scale_d = 16.0 * pow(B, (double)l) - 1.0;
        const long long res = (long long)ceil(scale_d) + 1;
        lp.scale[l] = (float)scale_d;
        lp.res[l]   = (uint32_t)res;
        if (res * res * res > (long long)kT) mask |= (1u << l);
    }
    lp.hashed_mask = mask;

    dim3 block(256);
    dim3 grid((unsigned)((n + 255) / 256));
    hipLaunchKernelGGL(ngp_mask_kernel, grid, block, 0, stream,
                       uvi, table, W1, b1, W2, b2, out, n, lp);
}